// Round 20
// baseline (521.475 us; speedup 1.0000x reference)
//
#include <hip/hip_runtime.h>

#define HDIM 64
#define NSTEPS 4

typedef __attribute__((ext_vector_type(4))) float f32x4;
typedef __attribute__((ext_vector_type(8))) short bf16x8;
typedef unsigned int uint;

union FragU { uint u[4]; uint4 u4; bf16x8 v; };

__device__ inline uint cvt_pk_bf16(float a, float b) {
  uint d;
  asm("v_cvt_pk_bf16_f32 %0, %1, %2" : "=v"(d) : "v"(a), "v"(b));
  return d;  // low16 = bf16(a), high16 = bf16(b), RNE
}
__device__ inline float lo_bf16_f32(uint p) { return __builtin_bit_cast(float, p << 16); }
__device__ inline float hi_bf16_f32(uint p) { return __builtin_bit_cast(float, p & 0xFFFF0000u); }

__device__ inline unsigned short rne_bf16u(float x) {
  uint u = __builtin_bit_cast(uint, x);
  uint r = u + 0x7FFFu + ((u >> 16) & 1u);
  return (unsigned short)(r >> 16);
}
__device__ inline float bf16f(unsigned short h) { return __builtin_bit_cast(float, ((uint)h) << 16); }

// Sum over the 16 lanes of a DPP row via rotate-reduce (pure VALU; result in
// every lane of the row).
__device__ inline float row_sum16(float x) {
  int v = __builtin_bit_cast(int, x);
  x += __builtin_bit_cast(float, __builtin_amdgcn_update_dpp(0, v, 0x128, 0xF, 0xF, true));
  v = __builtin_bit_cast(int, x);
  x += __builtin_bit_cast(float, __builtin_amdgcn_update_dpp(0, v, 0x124, 0xF, 0xF, true));
  v = __builtin_bit_cast(int, x);
  x += __builtin_bit_cast(float, __builtin_amdgcn_update_dpp(0, v, 0x122, 0xF, 0xF, true));
  v = __builtin_bit_cast(int, x);
  x += __builtin_bit_cast(float, __builtin_amdgcn_update_dpp(0, v, 0x121, 0xF, 0xF, true));
  return x;
}

// Pack a value pair to bf16 hi-plane + residual lo-plane dwords.
__device__ inline void pack2(float x0, float x1, uint& H, uint& L) {
  uint h = cvt_pk_bf16(x0, x1);
  H = h;
  L = cvt_pk_bf16(x0 - lo_bf16_f32(h), x1 - hi_bf16_f32(h));
}

// Layer-1 activation chain. Sigmoid from softplus: sigmoid(a) = 1 - e^{-sp}
// (since e^{-sp} = 1/(1+e^a)). Removes the rcp/cmp/cndmask path.
__device__ inline void l1chain(float4 par, float base, float s0, float s1,
                               float& sp, float& sg) {
  float a = fmaf(par.y, s0, fmaf(par.z, s1, base));
  float ex = __expf(-fabsf(a));
  float lg = __logf(1.0f + ex);
  sp = fmaxf(a, 0.f) + lg;
  sg = 1.0f - __expf(-sp);
}

// ws layout (dword offsets) — identical to rounds 8-19 (planes 1 and 3 are
// written by prep but no longer consumed by main):
//   [0,    8192): fragment planes, 2048 dw each:
//       mat0 = W2T hi, mat1 = W2T lo (unused), mat2 = QT hi, mat3 = QT lo (unused)
//     dword index within plane: ((kt*4+nt)*64 + lane)*4 + d
//     element pair (2d, 2d+1):  k = kt*32 + (lane>>4)*8 + 2d(+1), n(j) = nt*16 + (lane&15)
//   [8192, 8448): L1 per k: float4 (W1[k][0], W1[k][1], W1[k][2], b1[k])
//   [8448, 8576): C2 per j: float2 (W2[j][0], b2[j])
//   [8576, 8704): L3 per j: float2 (W3[0][j+1], W3[1][j+1])
//   [8704, 8708): C3: (W3[0][0], W3[1][0], b3[0], b3[1])

__global__ void ffjord_prep(const float* __restrict__ W1, const float* __restrict__ b1,
                            const float* __restrict__ W2, const float* __restrict__ b2,
                            const float* __restrict__ W3, const float* __restrict__ b3,
                            float* __restrict__ ws) {
  int tid = threadIdx.x;  // single block, 256 threads
  uint* wsu = (uint*)ws;
  for (int e2 = tid; e2 < 8192; e2 += 256) {
    int mat = e2 >> 11;
    int rem = e2 & 2047;
    int fr  = rem >> 8;          // kt*4+nt
    int l   = (rem >> 2) & 63;
    int d   = rem & 3;
    int kt = fr >> 2, nt = fr & 3;
    int g = l >> 4, cc = l & 15;
    int k0 = kt * 32 + g * 8 + 2 * d;
    int j  = nt * 16 + cc;
    float v0, v1;
    if (mat < 2) {
      v0 = W2[j * 65 + k0 + 1];
      v1 = W2[j * 65 + k0 + 2];
    } else {
      float p0 = W1[k0 * 3 + 1] * W3[j + 1] + W1[k0 * 3 + 2] * W3[65 + j + 1];
      float p1 = W1[(k0 + 1) * 3 + 1] * W3[j + 1] + W1[(k0 + 1) * 3 + 2] * W3[65 + j + 1];
      v0 = p0 * W2[j * 65 + k0 + 1];
      v1 = p1 * W2[j * 65 + k0 + 2];
    }
    unsigned short h0 = rne_bf16u(v0), h1 = rne_bf16u(v1);
    if (mat & 1) {  // lo plane = bf16 of residual
      h0 = rne_bf16u(v0 - bf16f(rne_bf16u(v0)));
      h1 = rne_bf16u(v1 - bf16f(rne_bf16u(v1)));
    }
    wsu[e2] = (uint)h0 | ((uint)h1 << 16);
  }
  if (tid < HDIM) {
    ws[8192 + tid * 4 + 0] = W1[tid * 3 + 0];
    ws[8192 + tid * 4 + 1] = W1[tid * 3 + 1];
    ws[8192 + tid * 4 + 2] = W1[tid * 3 + 2];
    ws[8192 + tid * 4 + 3] = b1[tid];
    ws[8448 + tid * 2 + 0] = W2[tid * 65 + 0];
    ws[8448 + tid * 2 + 1] = b2[tid];
    ws[8576 + tid * 2 + 0] = W3[tid + 1];
    ws[8576 + tid * 2 + 1] = W3[65 + tid + 1];
  }
  if (tid == 0) {
    ws[8704] = W3[0];
    ws[8705] = W3[65];
    ws[8706] = b3[0];
    ws[8707] = b3[1];
  }
}

// r19 kernel (475 µs, tripwire-clean, VGPR 80, zero spill) with ONE change:
// __launch_bounds__(256,4). r19's occupancy (27% = 2.2 waves/SIMD) was bound
// by the (256,2) block cap, NOT registers — at VGPR 80 the HW allows 6
// waves/SIMD. (256,4) caps VGPR at 128 (> natural 80 -> no squeeze pressure,
// unlike r14's cap-170-vs-natural-132 spill) and raises residency to 4
// blocks/CU (LDS 20480x4 = 80 KB, not binding). Issue floor ~110 µs vs 475
// measured -> stall-bound; doubled residency converts stall to overlap.
// Checkpoints: WRITE ~3 MB (no spill), Occupancy >= 40%.
__global__ __launch_bounds__(256, 4) void ffjord_main(
    const float* __restrict__ z_in, const float* __restrict__ dlp_in,
    const float* __restrict__ ws, float* __restrict__ out, int B) {
  __shared__ uint4 fragLds[1024];        // 16 KB: W2T hi | QT hi
  __shared__ float4 l1Lds[64];           // 1 KB
  __shared__ float2 c2Lds[64];           // 512 B
  __shared__ float2 l3Lds[64];           // 512 B
  __shared__ float  redLds[4][2][64];    // 2 KB   -> total 20480 B

  int tid = threadIdx.x;
  const uint4* wsu4 = (const uint4*)ws;
  // LDS[0..512) = ws plane0 (W2T hi); LDS[512..1024) = ws plane2 (QT hi).
  #pragma unroll
  for (int j = 0; j < 2; ++j) fragLds[tid + 256 * j] = wsu4[tid + 256 * j];
  #pragma unroll
  for (int j = 2; j < 4; ++j) fragLds[tid + 256 * j] = wsu4[tid + 256 * j + 512];
  if (tid < 64) {
    l1Lds[tid] = ((const float4*)(ws + 8192))[tid];
    c2Lds[tid] = ((const float2*)(ws + 8448))[tid];
    l3Lds[tid] = ((const float2*)(ws + 8576))[tid];
  }
  __syncthreads();

  const float c30 = ws[8704], c31 = ws[8705], cb0 = ws[8706], cb1 = ws[8707];

  int wid = tid >> 6, l = tid & 63;
  int g = l >> 4, c = l & 15;
  int pt = blockIdx.x * 256 + wid * 64 + l;
  int ptc = pt < B ? pt : (B - 1);

  float z0 = z_in[2 * ptc], z1 = z_in[2 * ptc + 1];
  float lp = dlp_in[ptc];
  const float dt = 1.0f / NSTEPS;

  // Deferred dv accumulators: per lane, w-weighted partials for the 4 mt-tiles
  // (pair 0 -> mt 0/1, pair 1 -> mt 2/3). Reduced once at kernel end.
  float acc0A[4] = {0.f, 0.f, 0.f, 0.f}, acc0B[4] = {0.f, 0.f, 0.f, 0.f};
  float acc1A[4] = {0.f, 0.f, 0.f, 0.f}, acc1B[4] = {0.f, 0.f, 0.f, 0.f};

  #pragma unroll 1
  for (int step = 0; step < NSTEPS; ++step) {
    float t0 = step * dt;
    float az0 = 0.f, az1 = 0.f;
    float zt0 = z0, zt1 = z1, ts = t0;

    #pragma unroll 1
    for (int s = 0; s < 4; ++s) {
      float w = (s == 1 || s == 2) ? 2.0f : 1.0f;
      float c2n[4];
      #pragma unroll
      for (int nt = 0; nt < 4; ++nt) {
        float2 cc = c2Lds[nt * 16 + c];
        c2n[nt] = fmaf(cc.x, ts, cc.y);
      }

      #pragma unroll 1
      for (int p = 0; p < 2; ++p) {
        asm volatile("" ::: "memory");  // pin pair-invariant LDS loads per pair
        int mtA = 2 * p, mtB = 2 * p + 1;
        // zt for this lane's A-rows, via wave-local shuffle (point = mt*16+c)
        float sA0 = __shfl(zt0, mtA * 16 + c);
        float sA1 = __shfl(zt1, mtA * 16 + c);
        float sB0 = __shfl(zt0, mtB * 16 + c);
        float sB1 = __shfl(zt1, mtB * 16 + c);

        // ---- A-frags for both row-tiles, packed incrementally ----
        // SP: hi+lo (activation residual kept). SG: hi only.
        FragU SPhA[2], SPlA[2], SGhA[2];
        FragU SPhB[2], SPlB[2], SGhB[2];
        #pragma unroll
        for (int kt = 0; kt < 2; ++kt) {
          #pragma unroll
          for (int d = 0; d < 4; ++d) {
            float4 p0 = l1Lds[kt * 32 + g * 8 + 2 * d];
            float4 p1 = l1Lds[kt * 32 + g * 8 + 2 * d + 1];
            float b0 = fmaf(p0.x, ts, p0.w);
            float b1 = fmaf(p1.x, ts, p1.w);
            float spA0, sgA0, spA1, sgA1, spB0, sgB0, spB1, sgB1;
            l1chain(p0, b0, sA0, sA1, spA0, sgA0);
            l1chain(p1, b1, sA0, sA1, spA1, sgA1);
            l1chain(p0, b0, sB0, sB1, spB0, sgB0);
            l1chain(p1, b1, sB0, sB1, spB1, sgB1);
            pack2(spA0, spA1, SPhA[kt].u[d], SPlA[kt].u[d]);
            pack2(spB0, spB1, SPhB[kt].u[d], SPlB[kt].u[d]);
            SGhA[kt].u[d] = cvt_pk_bf16(sgA0, sgA1);
            SGhB[kt].u[d] = cvt_pk_bf16(sgB0, sgB1);
          }
        }

        // ---- GEMM1 both rows (2-term: (SPh + SPl) x Bh), shared B reads ----
        // Accumulators init with c2n (h2 = C1 directly afterwards).
        f32x4 C1A[4], C1B[4];
        #pragma unroll
        for (int nt = 0; nt < 4; ++nt) {
          C1A[nt] = (f32x4){c2n[nt], c2n[nt], c2n[nt], c2n[nt]};
          C1B[nt] = (f32x4){c2n[nt], c2n[nt], c2n[nt], c2n[nt]};
        }
        #pragma unroll
        for (int kt = 0; kt < 2; ++kt) {
          #pragma unroll
          for (int nt = 0; nt < 4; ++nt) {
            FragU Bh;
            Bh.u4 = fragLds[(kt * 4 + nt) * 64 + l];
            C1A[nt] = __builtin_amdgcn_mfma_f32_16x16x32_bf16(SPhA[kt].v, Bh.v, C1A[nt], 0, 0, 0);
            C1B[nt] = __builtin_amdgcn_mfma_f32_16x16x32_bf16(SPhB[kt].v, Bh.v, C1B[nt], 0, 0, 0);
            C1A[nt] = __builtin_amdgcn_mfma_f32_16x16x32_bf16(SPlA[kt].v, Bh.v, C1A[nt], 0, 0, 0);
            C1B[nt] = __builtin_amdgcn_mfma_f32_16x16x32_bf16(SPlB[kt].v, Bh.v, C1B[nt], 0, 0, 0);
          }
        }

        // ---- fused mid + GEMM2 per nt: g transient, zd/dv accumulate ----
        float zp0A[4] = {0.f, 0.f, 0.f, 0.f}, zp1A[4] = {0.f, 0.f, 0.f, 0.f};
        float zp0B[4] = {0.f, 0.f, 0.f, 0.f}, zp1B[4] = {0.f, 0.f, 0.f, 0.f};
        float dvA[4] = {0.f, 0.f, 0.f, 0.f}, dvB[4] = {0.f, 0.f, 0.f, 0.f};
        #pragma unroll
        for (int nt = 0; nt < 4; ++nt) {
          float2 l3 = l3Lds[nt * 16 + c];
          float gAr[4], gBr[4];
          #pragma unroll
          for (int r = 0; r < 4; ++r) {
            {
              float h2 = C1A[nt][r];
              float ex = __expf(-fabsf(h2));
              float lg = __logf(1.0f + ex);
              float sq = fmaxf(h2, 0.f) + lg;
              gAr[r] = 1.0f - __expf(-sq);  // sigmoid(h2)
              zp0A[r] = fmaf(l3.x, sq, zp0A[r]);
              zp1A[r] = fmaf(l3.y, sq, zp1A[r]);
            }
            {
              float h2 = C1B[nt][r];
              float ex = __expf(-fabsf(h2));
              float lg = __logf(1.0f + ex);
              float sq = fmaxf(h2, 0.f) + lg;
              gBr[r] = 1.0f - __expf(-sq);  // sigmoid(h2)
              zp0B[r] = fmaf(l3.x, sq, zp0B[r]);
              zp1B[r] = fmaf(l3.y, sq, zp1B[r]);
            }
          }
          // GEMM2 nt-tile (A = SGh, B = QT hi only)
          f32x4 C2A = (f32x4){0.f, 0.f, 0.f, 0.f};
          f32x4 C2B = (f32x4){0.f, 0.f, 0.f, 0.f};
          #pragma unroll
          for (int kt = 0; kt < 2; ++kt) {
            FragU Bh;
            Bh.u4 = fragLds[512 + (kt * 4 + nt) * 64 + l];
            C2A = __builtin_amdgcn_mfma_f32_16x16x32_bf16(SGhA[kt].v, Bh.v, C2A, 0, 0, 0);
            C2B = __builtin_amdgcn_mfma_f32_16x16x32_bf16(SGhB[kt].v, Bh.v, C2B, 0, 0, 0);
          }
          #pragma unroll
          for (int r = 0; r < 4; ++r) {
            dvA[r] = fmaf(C2A[r], gAr[r], dvA[r]);
            dvB[r] = fmaf(C2B[r], gBr[r], dvB[r]);
          }
        }

        // zd reduce + store
        #pragma unroll
        for (int r = 0; r < 4; ++r) {
          zp0A[r] = row_sum16(zp0A[r]); zp1A[r] = row_sum16(zp1A[r]);
          zp0B[r] = row_sum16(zp0B[r]); zp1B[r] = row_sum16(zp1B[r]);
        }
        if (c == 0) {
          #pragma unroll
          for (int r = 0; r < 4; ++r) {
            redLds[wid][0][mtA * 16 + g * 4 + r] = zp0A[r];
            redLds[wid][1][mtA * 16 + g * 4 + r] = zp1A[r];
            redLds[wid][0][mtB * 16 + g * 4 + r] = zp0B[r];
            redLds[wid][1][mtB * 16 + g * 4 + r] = zp1B[r];
          }
        }

        // Deferred dv: accumulate w-weighted partials; reduce at kernel end.
        // Uniform branch keeps accumulator indices compile-time (rule #20).
        if (p == 0) {
          #pragma unroll
          for (int r = 0; r < 4; ++r) {
            acc0A[r] = fmaf(w, dvA[r], acc0A[r]);
            acc0B[r] = fmaf(w, dvB[r], acc0B[r]);
          }
        } else {
          #pragma unroll
          for (int r = 0; r < 4; ++r) {
            acc1A[r] = fmaf(w, dvA[r], acc1A[r]);
            acc1B[r] = fmaf(w, dvB[r], acc1B[r]);
          }
        }
      }

      // ---- explicit handoff barrier: redLds writes -> reads ----
      __syncthreads();

      // ---- owner: collect zd, RK4 ----
      float zd0 = redLds[wid][0][l] + fmaf(c30, ts, cb0);
      float zd1 = redLds[wid][1][l] + fmaf(c31, ts, cb1);

      az0 = fmaf(w, zd0, az0);
      az1 = fmaf(w, zd1, az1);
      if (s < 3) {
        float cc2 = (s == 2) ? dt : 0.5f * dt;
        zt0 = fmaf(cc2, zd0, z0);
        zt1 = fmaf(cc2, zd1, z1);
        ts = t0 + cc2;
      }
    }
    z0 = fmaf(dt / 6.0f, az0, z0);
    z1 = fmaf(dt / 6.0f, az1, z1);
  }

  // ---- final deferred dv reduction (once per kernel) ----
  #pragma unroll
  for (int r = 0; r < 4; ++r) {
    acc0A[r] = row_sum16(acc0A[r]);
    acc0B[r] = row_sum16(acc0B[r]);
    acc1A[r] = row_sum16(acc1A[r]);
    acc1B[r] = row_sum16(acc1B[r]);
  }
  if (c == 0) {
    #pragma unroll
    for (int r = 0; r < 4; ++r) {
      redLds[wid][0][0 * 16 + g * 4 + r] = acc0A[r];
      redLds[wid][0][1 * 16 + g * 4 + r] = acc0B[r];
      redLds[wid][0][2 * 16 + g * 4 + r] = acc1A[r];
      redLds[wid][0][3 * 16 + g * 4 + r] = acc1B[r];
    }
  }
  __syncthreads();
  float alTot = redLds[wid][0][l];
  lp = fmaf(-dt / 6.0f, alTot, lp);  // k_l = -div, summed over all stages/steps

  if (pt < B) {
    out[2 * pt] = z0;
    out[2 * pt + 1] = z1;
    out[2 * B + pt] = lp;
  }
}

extern "C" void kernel_launch(void* const* d_in, const int* in_sizes, int n_in,
                              void* d_out, int out_size, void* d_ws, size_t ws_size,
                              hipStream_t stream) {
  const float* z   = (const float*)d_in[0];
  const float* dlp = (const float*)d_in[1];
  const float* W1  = (const float*)d_in[2];
  const float* b1  = (const float*)d_in[3];
  const float* W2  = (const float*)d_in[4];
  const float* b2  = (const float*)d_in[5];
  const float* W3  = (const float*)d_in[6];
  const float* b3  = (const float*)d_in[7];
  float* out = (float*)d_out;
  float* ws = (float*)d_ws;

  int B = in_sizes[0] / 2;

  ffjord_prep<<<1, 256, 0, stream>>>(W1, b1, W2, b2, W3, b3, ws);
  int blocks = (B + 255) / 256;  // 256 points per block, 64 per wave
  ffjord_main<<<blocks, 256, 0, stream>>>(z, dlp, ws, out, B);
}

// Round 21
// 492.055 us; speedup vs baseline: 1.0598x; 1.0598x over previous
//
#include <hip/hip_runtime.h>

#define HDIM 64
#define NSTEPS 4

typedef __attribute__((ext_vector_type(4))) float f32x4;
typedef __attribute__((ext_vector_type(8))) short bf16x8;
typedef unsigned int uint;

union FragU { uint u[4]; uint4 u4; bf16x8 v; };

// Wave-local LDS handoff fence: redLds is wave-private (indexed by own wid),
// so cross-wave __syncthreads is overkill — we only need (a) HW: drain the
// DS queue (lgkmcnt(0)) and (b) compiler: forbid reordering reads before the
// exec-masked writes (memory clobber + sched_barrier, per rule #18).
#define WAVE_FENCE() do { \
  asm volatile("s_waitcnt lgkmcnt(0)" ::: "memory"); \
  __builtin_amdgcn_sched_barrier(0); \
} while (0)

__device__ inline uint cvt_pk_bf16(float a, float b) {
  uint d;
  asm("v_cvt_pk_bf16_f32 %0, %1, %2" : "=v"(d) : "v"(a), "v"(b));
  return d;  // low16 = bf16(a), high16 = bf16(b), RNE
}
__device__ inline float lo_bf16_f32(uint p) { return __builtin_bit_cast(float, p << 16); }
__device__ inline float hi_bf16_f32(uint p) { return __builtin_bit_cast(float, p & 0xFFFF0000u); }

__device__ inline unsigned short rne_bf16u(float x) {
  uint u = __builtin_bit_cast(uint, x);
  uint r = u + 0x7FFFu + ((u >> 16) & 1u);
  return (unsigned short)(r >> 16);
}
__device__ inline float bf16f(unsigned short h) { return __builtin_bit_cast(float, ((uint)h) << 16); }

// Sum over the 16 lanes of a DPP row via rotate-reduce (pure VALU; result in
// every lane of the row).
__device__ inline float row_sum16(float x) {
  int v = __builtin_bit_cast(int, x);
  x += __builtin_bit_cast(float, __builtin_amdgcn_update_dpp(0, v, 0x128, 0xF, 0xF, true));
  v = __builtin_bit_cast(int, x);
  x += __builtin_bit_cast(float, __builtin_amdgcn_update_dpp(0, v, 0x124, 0xF, 0xF, true));
  v = __builtin_bit_cast(int, x);
  x += __builtin_bit_cast(float, __builtin_amdgcn_update_dpp(0, v, 0x122, 0xF, 0xF, true));
  v = __builtin_bit_cast(int, x);
  x += __builtin_bit_cast(float, __builtin_amdgcn_update_dpp(0, v, 0x121, 0xF, 0xF, true));
  return x;
}

// Pack a value pair to bf16 hi-plane + residual lo-plane dwords.
__device__ inline void pack2(float x0, float x1, uint& H, uint& L) {
  uint h = cvt_pk_bf16(x0, x1);
  H = h;
  L = cvt_pk_bf16(x0 - lo_bf16_f32(h), x1 - hi_bf16_f32(h));
}

// Layer-1 activation chain. Sigmoid from softplus: sigmoid(a) = 1 - e^{-sp}
// (since e^{-sp} = 1/(1+e^a)). Removes the rcp/cmp/cndmask path.
__device__ inline void l1chain(float4 par, float base, float s0, float s1,
                               float& sp, float& sg) {
  float a = fmaf(par.y, s0, fmaf(par.z, s1, base));
  float ex = __expf(-fabsf(a));
  float lg = __logf(1.0f + ex);
  sp = fmaxf(a, 0.f) + lg;
  sg = 1.0f - __expf(-sp);
}

// ws layout (dword offsets) — identical to rounds 8-20 (planes 1 and 3 are
// written by prep but no longer consumed by main):
//   [0,    8192): fragment planes, 2048 dw each:
//       mat0 = W2T hi, mat1 = W2T lo (unused), mat2 = QT hi, mat3 = QT lo (unused)
//     dword index within plane: ((kt*4+nt)*64 + lane)*4 + d
//     element pair (2d, 2d+1):  k = kt*32 + (lane>>4)*8 + 2d(+1), n(j) = nt*16 + (lane&15)
//   [8192, 8448): L1 per k: float4 (W1[k][0], W1[k][1], W1[k][2], b1[k])
//   [8448, 8576): C2 per j: float2 (W2[j][0], b2[j])
//   [8576, 8704): L3 per j: float2 (W3[0][j+1], W3[1][j+1])
//   [8704, 8708): C3: (W3[0][0], W3[1][0], b3[0], b3[1])

__global__ void ffjord_prep(const float* __restrict__ W1, const float* __restrict__ b1,
                            const float* __restrict__ W2, const float* __restrict__ b2,
                            const float* __restrict__ W3, const float* __restrict__ b3,
                            float* __restrict__ ws) {
  int tid = threadIdx.x;  // single block, 256 threads
  uint* wsu = (uint*)ws;
  for (int e2 = tid; e2 < 8192; e2 += 256) {
    int mat = e2 >> 11;
    int rem = e2 & 2047;
    int fr  = rem >> 8;          // kt*4+nt
    int l   = (rem >> 2) & 63;
    int d   = rem & 3;
    int kt = fr >> 2, nt = fr & 3;
    int g = l >> 4, cc = l & 15;
    int k0 = kt * 32 + g * 8 + 2 * d;
    int j  = nt * 16 + cc;
    float v0, v1;
    if (mat < 2) {
      v0 = W2[j * 65 + k0 + 1];
      v1 = W2[j * 65 + k0 + 2];
    } else {
      float p0 = W1[k0 * 3 + 1] * W3[j + 1] + W1[k0 * 3 + 2] * W3[65 + j + 1];
      float p1 = W1[(k0 + 1) * 3 + 1] * W3[j + 1] + W1[(k0 + 1) * 3 + 2] * W3[65 + j + 1];
      v0 = p0 * W2[j * 65 + k0 + 1];
      v1 = p1 * W2[j * 65 + k0 + 2];
    }
    unsigned short h0 = rne_bf16u(v0), h1 = rne_bf16u(v1);
    if (mat & 1) {  // lo plane = bf16 of residual
      h0 = rne_bf16u(v0 - bf16f(rne_bf16u(v0)));
      h1 = rne_bf16u(v1 - bf16f(rne_bf16u(v1)));
    }
    wsu[e2] = (uint)h0 | ((uint)h1 << 16);
  }
  if (tid < HDIM) {
    ws[8192 + tid * 4 + 0] = W1[tid * 3 + 0];
    ws[8192 + tid * 4 + 1] = W1[tid * 3 + 1];
    ws[8192 + tid * 4 + 2] = W1[tid * 3 + 2];
    ws[8192 + tid * 4 + 3] = b1[tid];
    ws[8448 + tid * 2 + 0] = W2[tid * 65 + 0];
    ws[8448 + tid * 2 + 1] = b2[tid];
    ws[8576 + tid * 2 + 0] = W3[tid + 1];
    ws[8576 + tid * 2 + 1] = W3[65 + tid + 1];
  }
  if (tid == 0) {
    ws[8704] = W3[0];
    ws[8705] = W3[65];
    ws[8706] = b3[0];
    ws[8707] = b3[1];
  }
}

// r19 kernel (475 µs, tripwire-clean, VGPR 80, zero spill) with the 17
// per-eval __syncthreads() replaced by WAVE-LOCAL fences. redLds[wid] is
// wave-private: the r18 hazard was compiler reordering of the exec-masked
// ds_write -> full-wave ds_read handoff WITHIN a wave, not an inter-wave
// race. s_waitcnt lgkmcnt(0) + sched_barrier(0) (rule #18) enforces it
// without forcing the block's 4 independent waves into lockstep 17x —
// that rendezvous destroyed cross-wave phase offset at 2.2 waves/SIMD.
// The single genuine inter-wave barrier (fragLds staging) stays.
// (256,2) kept: the unique no-spill launch-bounds point (cap = 256/n law:
// 256/128/85/64 for n=1..4; natural live set 80).
// Checkpoints: tripwire passes, WRITE ~3 MB, dur < 475.
__global__ __launch_bounds__(256, 2) void ffjord_main(
    const float* __restrict__ z_in, const float* __restrict__ dlp_in,
    const float* __restrict__ ws, float* __restrict__ out, int B) {
  __shared__ uint4 fragLds[1024];        // 16 KB: W2T hi | QT hi
  __shared__ float4 l1Lds[64];           // 1 KB
  __shared__ float2 c2Lds[64];           // 512 B
  __shared__ float2 l3Lds[64];           // 512 B
  __shared__ float  redLds[4][2][64];    // 2 KB   -> total 20480 B

  int tid = threadIdx.x;
  const uint4* wsu4 = (const uint4*)ws;
  // LDS[0..512) = ws plane0 (W2T hi); LDS[512..1024) = ws plane2 (QT hi).
  #pragma unroll
  for (int j = 0; j < 2; ++j) fragLds[tid + 256 * j] = wsu4[tid + 256 * j];
  #pragma unroll
  for (int j = 2; j < 4; ++j) fragLds[tid + 256 * j] = wsu4[tid + 256 * j + 512];
  if (tid < 64) {
    l1Lds[tid] = ((const float4*)(ws + 8192))[tid];
    c2Lds[tid] = ((const float2*)(ws + 8448))[tid];
    l3Lds[tid] = ((const float2*)(ws + 8576))[tid];
  }
  __syncthreads();  // genuine inter-wave handoff: fragLds/l1Lds staging

  const float c30 = ws[8704], c31 = ws[8705], cb0 = ws[8706], cb1 = ws[8707];

  int wid = tid >> 6, l = tid & 63;
  int g = l >> 4, c = l & 15;
  int pt = blockIdx.x * 256 + wid * 64 + l;
  int ptc = pt < B ? pt : (B - 1);

  float z0 = z_in[2 * ptc], z1 = z_in[2 * ptc + 1];
  float lp = dlp_in[ptc];
  const float dt = 1.0f / NSTEPS;

  // Deferred dv accumulators: per lane, w-weighted partials for the 4 mt-tiles
  // (pair 0 -> mt 0/1, pair 1 -> mt 2/3). Reduced once at kernel end.
  float acc0A[4] = {0.f, 0.f, 0.f, 0.f}, acc0B[4] = {0.f, 0.f, 0.f, 0.f};
  float acc1A[4] = {0.f, 0.f, 0.f, 0.f}, acc1B[4] = {0.f, 0.f, 0.f, 0.f};

  #pragma unroll 1
  for (int step = 0; step < NSTEPS; ++step) {
    float t0 = step * dt;
    float az0 = 0.f, az1 = 0.f;
    float zt0 = z0, zt1 = z1, ts = t0;

    #pragma unroll 1
    for (int s = 0; s < 4; ++s) {
      float w = (s == 1 || s == 2) ? 2.0f : 1.0f;
      float c2n[4];
      #pragma unroll
      for (int nt = 0; nt < 4; ++nt) {
        float2 cc = c2Lds[nt * 16 + c];
        c2n[nt] = fmaf(cc.x, ts, cc.y);
      }

      #pragma unroll 1
      for (int p = 0; p < 2; ++p) {
        asm volatile("" ::: "memory");  // pin pair-invariant LDS loads per pair
        int mtA = 2 * p, mtB = 2 * p + 1;
        // zt for this lane's A-rows, via wave-local shuffle (point = mt*16+c)
        float sA0 = __shfl(zt0, mtA * 16 + c);
        float sA1 = __shfl(zt1, mtA * 16 + c);
        float sB0 = __shfl(zt0, mtB * 16 + c);
        float sB1 = __shfl(zt1, mtB * 16 + c);

        // ---- A-frags for both row-tiles, packed incrementally ----
        // SP: hi+lo (activation residual kept). SG: hi only.
        FragU SPhA[2], SPlA[2], SGhA[2];
        FragU SPhB[2], SPlB[2], SGhB[2];
        #pragma unroll
        for (int kt = 0; kt < 2; ++kt) {
          #pragma unroll
          for (int d = 0; d < 4; ++d) {
            float4 p0 = l1Lds[kt * 32 + g * 8 + 2 * d];
            float4 p1 = l1Lds[kt * 32 + g * 8 + 2 * d + 1];
            float b0 = fmaf(p0.x, ts, p0.w);
            float b1 = fmaf(p1.x, ts, p1.w);
            float spA0, sgA0, spA1, sgA1, spB0, sgB0, spB1, sgB1;
            l1chain(p0, b0, sA0, sA1, spA0, sgA0);
            l1chain(p1, b1, sA0, sA1, spA1, sgA1);
            l1chain(p0, b0, sB0, sB1, spB0, sgB0);
            l1chain(p1, b1, sB0, sB1, spB1, sgB1);
            pack2(spA0, spA1, SPhA[kt].u[d], SPlA[kt].u[d]);
            pack2(spB0, spB1, SPhB[kt].u[d], SPlB[kt].u[d]);
            SGhA[kt].u[d] = cvt_pk_bf16(sgA0, sgA1);
            SGhB[kt].u[d] = cvt_pk_bf16(sgB0, sgB1);
          }
        }

        // ---- GEMM1 both rows (2-term: (SPh + SPl) x Bh), shared B reads ----
        // Accumulators init with c2n (h2 = C1 directly afterwards).
        f32x4 C1A[4], C1B[4];
        #pragma unroll
        for (int nt = 0; nt < 4; ++nt) {
          C1A[nt] = (f32x4){c2n[nt], c2n[nt], c2n[nt], c2n[nt]};
          C1B[nt] = (f32x4){c2n[nt], c2n[nt], c2n[nt], c2n[nt]};
        }
        #pragma unroll
        for (int kt = 0; kt < 2; ++kt) {
          #pragma unroll
          for (int nt = 0; nt < 4; ++nt) {
            FragU Bh;
            Bh.u4 = fragLds[(kt * 4 + nt) * 64 + l];
            C1A[nt] = __builtin_amdgcn_mfma_f32_16x16x32_bf16(SPhA[kt].v, Bh.v, C1A[nt], 0, 0, 0);
            C1B[nt] = __builtin_amdgcn_mfma_f32_16x16x32_bf16(SPhB[kt].v, Bh.v, C1B[nt], 0, 0, 0);
            C1A[nt] = __builtin_amdgcn_mfma_f32_16x16x32_bf16(SPlA[kt].v, Bh.v, C1A[nt], 0, 0, 0);
            C1B[nt] = __builtin_amdgcn_mfma_f32_16x16x32_bf16(SPlB[kt].v, Bh.v, C1B[nt], 0, 0, 0);
          }
        }

        // ---- fused mid + GEMM2 per nt: g transient, zd/dv accumulate ----
        float zp0A[4] = {0.f, 0.f, 0.f, 0.f}, zp1A[4] = {0.f, 0.f, 0.f, 0.f};
        float zp0B[4] = {0.f, 0.f, 0.f, 0.f}, zp1B[4] = {0.f, 0.f, 0.f, 0.f};
        float dvA[4] = {0.f, 0.f, 0.f, 0.f}, dvB[4] = {0.f, 0.f, 0.f, 0.f};
        #pragma unroll
        for (int nt = 0; nt < 4; ++nt) {
          float2 l3 = l3Lds[nt * 16 + c];
          float gAr[4], gBr[4];
          #pragma unroll
          for (int r = 0; r < 4; ++r) {
            {
              float h2 = C1A[nt][r];
              float ex = __expf(-fabsf(h2));
              float lg = __logf(1.0f + ex);
              float sq = fmaxf(h2, 0.f) + lg;
              gAr[r] = 1.0f - __expf(-sq);  // sigmoid(h2)
              zp0A[r] = fmaf(l3.x, sq, zp0A[r]);
              zp1A[r] = fmaf(l3.y, sq, zp1A[r]);
            }
            {
              float h2 = C1B[nt][r];
              float ex = __expf(-fabsf(h2));
              float lg = __logf(1.0f + ex);
              float sq = fmaxf(h2, 0.f) + lg;
              gBr[r] = 1.0f - __expf(-sq);  // sigmoid(h2)
              zp0B[r] = fmaf(l3.x, sq, zp0B[r]);
              zp1B[r] = fmaf(l3.y, sq, zp1B[r]);
            }
          }
          // GEMM2 nt-tile (A = SGh, B = QT hi only)
          f32x4 C2A = (f32x4){0.f, 0.f, 0.f, 0.f};
          f32x4 C2B = (f32x4){0.f, 0.f, 0.f, 0.f};
          #pragma unroll
          for (int kt = 0; kt < 2; ++kt) {
            FragU Bh;
            Bh.u4 = fragLds[512 + (kt * 4 + nt) * 64 + l];
            C2A = __builtin_amdgcn_mfma_f32_16x16x32_bf16(SGhA[kt].v, Bh.v, C2A, 0, 0, 0);
            C2B = __builtin_amdgcn_mfma_f32_16x16x32_bf16(SGhB[kt].v, Bh.v, C2B, 0, 0, 0);
          }
          #pragma unroll
          for (int r = 0; r < 4; ++r) {
            dvA[r] = fmaf(C2A[r], gAr[r], dvA[r]);
            dvB[r] = fmaf(C2B[r], gBr[r], dvB[r]);
          }
        }

        // zd reduce + store
        #pragma unroll
        for (int r = 0; r < 4; ++r) {
          zp0A[r] = row_sum16(zp0A[r]); zp1A[r] = row_sum16(zp1A[r]);
          zp0B[r] = row_sum16(zp0B[r]); zp1B[r] = row_sum16(zp1B[r]);
        }
        if (c == 0) {
          #pragma unroll
          for (int r = 0; r < 4; ++r) {
            redLds[wid][0][mtA * 16 + g * 4 + r] = zp0A[r];
            redLds[wid][1][mtA * 16 + g * 4 + r] = zp1A[r];
            redLds[wid][0][mtB * 16 + g * 4 + r] = zp0B[r];
            redLds[wid][1][mtB * 16 + g * 4 + r] = zp1B[r];
          }
        }

        // Deferred dv: accumulate w-weighted partials; reduce at kernel end.
        // Uniform branch keeps accumulator indices compile-time (rule #20).
        if (p == 0) {
          #pragma unroll
          for (int r = 0; r < 4; ++r) {
            acc0A[r] = fmaf(w, dvA[r], acc0A[r]);
            acc0B[r] = fmaf(w, dvB[r], acc0B[r]);
          }
        } else {
          #pragma unroll
          for (int r = 0; r < 4; ++r) {
            acc1A[r] = fmaf(w, dvA[r], acc1A[r]);
            acc1B[r] = fmaf(w, dvB[r], acc1B[r]);
          }
        }
      }

      // ---- wave-local handoff: redLds writes -> reads (same wave only) ----
      WAVE_FENCE();

      // ---- owner: collect zd, RK4 ----
      float zd0 = redLds[wid][0][l] + fmaf(c30, ts, cb0);
      float zd1 = redLds[wid][1][l] + fmaf(c31, ts, cb1);

      az0 = fmaf(w, zd0, az0);
      az1 = fmaf(w, zd1, az1);
      if (s < 3) {
        float cc2 = (s == 2) ? dt : 0.5f * dt;
        zt0 = fmaf(cc2, zd0, z0);
        zt1 = fmaf(cc2, zd1, z1);
        ts = t0 + cc2;
      }
    }
    z0 = fmaf(dt / 6.0f, az0, z0);
    z1 = fmaf(dt / 6.0f, az1, z1);
  }

  // ---- final deferred dv reduction (once per kernel) ----
  #pragma unroll
  for (int r = 0; r < 4; ++r) {
    acc0A[r] = row_sum16(acc0A[r]);
    acc0B[r] = row_sum16(acc0B[r]);
    acc1A[r] = row_sum16(acc1A[r]);
    acc1B[r] = row_sum16(acc1B[r]);
  }
  if (c == 0) {
    #pragma unroll
    for (int r = 0; r < 4; ++r) {
      redLds[wid][0][0 * 16 + g * 4 + r] = acc0A[r];
      redLds[wid][0][1 * 16 + g * 4 + r] = acc0B[r];
      redLds[wid][0][2 * 16 + g * 4 + r] = acc1A[r];
      redLds[wid][0][3 * 16 + g * 4 + r] = acc1B[r];
    }
  }
  WAVE_FENCE();
  float alTot = redLds[wid][0][l];
  lp = fmaf(-dt / 6.0f, alTot, lp);  // k_l = -div, summed over all stages/steps

  if (pt < B) {
    out[2 * pt] = z0;
    out[2 * pt + 1] = z1;
    out[2 * B + pt] = lp;
  }
}

extern "C" void kernel_launch(void* const* d_in, const int* in_sizes, int n_in,
                              void* d_out, int out_size, void* d_ws, size_t ws_size,
                              hipStream_t stream) {
  const float* z   = (const float*)d_in[0];
  const float* dlp = (const float*)d_in[1];
  const float* W1  = (const float*)d_in[2];
  const float* b1  = (const float*)d_in[3];
  const float* W2  = (const float*)d_in[4];
  const float* b2  = (const float*)d_in[5];
  const float* W3  = (const float*)d_in[6];
  const float* b3  = (const float*)d_in[7];
  float* out = (float*)d_out;
  float* ws = (float*)d_ws;

  int B = in_sizes[0] / 2;

  ffjord_prep<<<1, 256, 0, stream>>>(W1, b1, W2, b2, W3, b3, ws);
  int blocks = (B + 255) / 256;  // 256 points per block, 64 per wave
  ffjord_main<<<blocks, 256, 0, stream>>>(z, dlp, ws, out, B);
}

// Round 22
// 491.326 us; speedup vs baseline: 1.0614x; 1.0015x over previous
//
#include <hip/hip_runtime.h>

#define HDIM 64
#define NSTEPS 4

typedef __attribute__((ext_vector_type(4))) float f32x4;
typedef __attribute__((ext_vector_type(8))) short bf16x8;
typedef unsigned int uint;

union FragU { uint u[4]; uint4 u4; bf16x8 v; };

// Wave-local LDS handoff fence: redLds is wave-private (indexed by own wid),
// so cross-wave __syncthreads is overkill — we only need (a) HW: drain the
// DS queue (lgkmcnt(0)) and (b) compiler: forbid reordering reads before the
// exec-masked writes (memory clobber + sched_barrier, per rule #18).
#define WAVE_FENCE() do { \
  asm volatile("s_waitcnt lgkmcnt(0)" ::: "memory"); \
  __builtin_amdgcn_sched_barrier(0); \
} while (0)

__device__ inline uint cvt_pk_bf16(float a, float b) {
  uint d;
  asm("v_cvt_pk_bf16_f32 %0, %1, %2" : "=v"(d) : "v"(a), "v"(b));
  return d;  // low16 = bf16(a), high16 = bf16(b), RNE
}
__device__ inline float lo_bf16_f32(uint p) { return __builtin_bit_cast(float, p << 16); }
__device__ inline float hi_bf16_f32(uint p) { return __builtin_bit_cast(float, p & 0xFFFF0000u); }

__device__ inline unsigned short rne_bf16u(float x) {
  uint u = __builtin_bit_cast(uint, x);
  uint r = u + 0x7FFFu + ((u >> 16) & 1u);
  return (unsigned short)(r >> 16);
}
__device__ inline float bf16f(unsigned short h) { return __builtin_bit_cast(float, ((uint)h) << 16); }

// Sum over the 16 lanes of a DPP row via rotate-reduce (pure VALU; result in
// every lane of the row).
__device__ inline float row_sum16(float x) {
  int v = __builtin_bit_cast(int, x);
  x += __builtin_bit_cast(float, __builtin_amdgcn_update_dpp(0, v, 0x128, 0xF, 0xF, true));
  v = __builtin_bit_cast(int, x);
  x += __builtin_bit_cast(float, __builtin_amdgcn_update_dpp(0, v, 0x124, 0xF, 0xF, true));
  v = __builtin_bit_cast(int, x);
  x += __builtin_bit_cast(float, __builtin_amdgcn_update_dpp(0, v, 0x122, 0xF, 0xF, true));
  v = __builtin_bit_cast(int, x);
  x += __builtin_bit_cast(float, __builtin_amdgcn_update_dpp(0, v, 0x121, 0xF, 0xF, true));
  return x;
}

// Pack a value pair to bf16 hi-plane + residual lo-plane dwords.
__device__ inline void pack2(float x0, float x1, uint& H, uint& L) {
  uint h = cvt_pk_bf16(x0, x1);
  H = h;
  L = cvt_pk_bf16(x0 - lo_bf16_f32(h), x1 - hi_bf16_f32(h));
}

// Layer-1 activation chain. Sigmoid from softplus: sigmoid(a) = 1 - e^{-sp}
// (since e^{-sp} = 1/(1+e^a)). Removes the rcp/cmp/cndmask path.
__device__ inline void l1chain(float4 par, float base, float s0, float s1,
                               float& sp, float& sg) {
  float a = fmaf(par.y, s0, fmaf(par.z, s1, base));
  float ex = __expf(-fabsf(a));
  float lg = __logf(1.0f + ex);
  sp = fmaxf(a, 0.f) + lg;
  sg = 1.0f - __expf(-sp);
}

// ws layout (dword offsets) — identical to rounds 8-21 (planes 1 and 3 are
// written by prep but no longer consumed by main):
//   [0,    8192): fragment planes, 2048 dw each:
//       mat0 = W2T hi, mat1 = W2T lo (unused), mat2 = QT hi, mat3 = QT lo (unused)
//     dword index within plane: ((kt*4+nt)*64 + lane)*4 + d
//     element pair (2d, 2d+1):  k = kt*32 + (lane>>4)*8 + 2d(+1), n(j) = nt*16 + (lane&15)
//   [8192, 8448): L1 per k: float4 (W1[k][0], W1[k][1], W1[k][2], b1[k])
//   [8448, 8576): C2 per j: float2 (W2[j][0], b2[j])
//   [8576, 8704): L3 per j: float2 (W3[0][j+1], W3[1][j+1])
//   [8704, 8708): C3: (W3[0][0], W3[1][0], b3[0], b3[1])

__global__ void ffjord_prep(const float* __restrict__ W1, const float* __restrict__ b1,
                            const float* __restrict__ W2, const float* __restrict__ b2,
                            const float* __restrict__ W3, const float* __restrict__ b3,
                            float* __restrict__ ws) {
  int tid = threadIdx.x;  // single block, 256 threads
  uint* wsu = (uint*)ws;
  for (int e2 = tid; e2 < 8192; e2 += 256) {
    int mat = e2 >> 11;
    int rem = e2 & 2047;
    int fr  = rem >> 8;          // kt*4+nt
    int l   = (rem >> 2) & 63;
    int d   = rem & 3;
    int kt = fr >> 2, nt = fr & 3;
    int g = l >> 4, cc = l & 15;
    int k0 = kt * 32 + g * 8 + 2 * d;
    int j  = nt * 16 + cc;
    float v0, v1;
    if (mat < 2) {
      v0 = W2[j * 65 + k0 + 1];
      v1 = W2[j * 65 + k0 + 2];
    } else {
      float p0 = W1[k0 * 3 + 1] * W3[j + 1] + W1[k0 * 3 + 2] * W3[65 + j + 1];
      float p1 = W1[(k0 + 1) * 3 + 1] * W3[j + 1] + W1[(k0 + 1) * 3 + 2] * W3[65 + j + 1];
      v0 = p0 * W2[j * 65 + k0 + 1];
      v1 = p1 * W2[j * 65 + k0 + 2];
    }
    unsigned short h0 = rne_bf16u(v0), h1 = rne_bf16u(v1);
    if (mat & 1) {  // lo plane = bf16 of residual
      h0 = rne_bf16u(v0 - bf16f(rne_bf16u(v0)));
      h1 = rne_bf16u(v1 - bf16f(rne_bf16u(v1)));
    }
    wsu[e2] = (uint)h0 | ((uint)h1 << 16);
  }
  if (tid < HDIM) {
    ws[8192 + tid * 4 + 0] = W1[tid * 3 + 0];
    ws[8192 + tid * 4 + 1] = W1[tid * 3 + 1];
    ws[8192 + tid * 4 + 2] = W1[tid * 3 + 2];
    ws[8192 + tid * 4 + 3] = b1[tid];
    ws[8448 + tid * 2 + 0] = W2[tid * 65 + 0];
    ws[8448 + tid * 2 + 1] = b2[tid];
    ws[8576 + tid * 2 + 0] = W3[tid + 1];
    ws[8576 + tid * 2 + 1] = W3[65 + tid + 1];
  }
  if (tid == 0) {
    ws[8704] = W3[0];
    ws[8705] = W3[65];
    ws[8706] = b3[0];
    ws[8707] = b3[1];
  }
}

// r21 kernel (473 µs, tripwire-clean, VGPR 80, zero spill) with ONE change:
// __launch_bounds__(256,3). The calibrated cap law (cap = 256/min_waves:
// 256/128/85/64 for n=1..4) says (256,3) caps VGPR at 85 — and r21 measured
// the NATURAL live set at 80 (allocated 80 under the unconstrained 128 cap),
// so it fits with slack. Unlike r14's (256,3) disaster (natural ~132 vs cap
// 85 -> massive squeeze+spill), this is a no-squeeze fit. 3 waves/SIMD =
// +50% residency on a kernel whose per-SIMD issue is ~50% (stall-dominated).
// LDS 20480x3 = 61 KB, not binding. Checkpoints: WRITE ~3 MB (no spill),
// Occupancy >= 37%. If spill appears: revert to (256,2), ~473 is the floor.
__global__ __launch_bounds__(256, 3) void ffjord_main(
    const float* __restrict__ z_in, const float* __restrict__ dlp_in,
    const float* __restrict__ ws, float* __restrict__ out, int B) {
  __shared__ uint4 fragLds[1024];        // 16 KB: W2T hi | QT hi
  __shared__ float4 l1Lds[64];           // 1 KB
  __shared__ float2 c2Lds[64];           // 512 B
  __shared__ float2 l3Lds[64];           // 512 B
  __shared__ float  redLds[4][2][64];    // 2 KB   -> total 20480 B

  int tid = threadIdx.x;
  const uint4* wsu4 = (const uint4*)ws;
  // LDS[0..512) = ws plane0 (W2T hi); LDS[512..1024) = ws plane2 (QT hi).
  #pragma unroll
  for (int j = 0; j < 2; ++j) fragLds[tid + 256 * j] = wsu4[tid + 256 * j];
  #pragma unroll
  for (int j = 2; j < 4; ++j) fragLds[tid + 256 * j] = wsu4[tid + 256 * j + 512];
  if (tid < 64) {
    l1Lds[tid] = ((const float4*)(ws + 8192))[tid];
    c2Lds[tid] = ((const float2*)(ws + 8448))[tid];
    l3Lds[tid] = ((const float2*)(ws + 8576))[tid];
  }
  __syncthreads();  // genuine inter-wave handoff: fragLds/l1Lds staging

  const float c30 = ws[8704], c31 = ws[8705], cb0 = ws[8706], cb1 = ws[8707];

  int wid = tid >> 6, l = tid & 63;
  int g = l >> 4, c = l & 15;
  int pt = blockIdx.x * 256 + wid * 64 + l;
  int ptc = pt < B ? pt : (B - 1);

  float z0 = z_in[2 * ptc], z1 = z_in[2 * ptc + 1];
  float lp = dlp_in[ptc];
  const float dt = 1.0f / NSTEPS;

  // Deferred dv accumulators: per lane, w-weighted partials for the 4 mt-tiles
  // (pair 0 -> mt 0/1, pair 1 -> mt 2/3). Reduced once at kernel end.
  float acc0A[4] = {0.f, 0.f, 0.f, 0.f}, acc0B[4] = {0.f, 0.f, 0.f, 0.f};
  float acc1A[4] = {0.f, 0.f, 0.f, 0.f}, acc1B[4] = {0.f, 0.f, 0.f, 0.f};

  #pragma unroll 1
  for (int step = 0; step < NSTEPS; ++step) {
    float t0 = step * dt;
    float az0 = 0.f, az1 = 0.f;
    float zt0 = z0, zt1 = z1, ts = t0;

    #pragma unroll 1
    for (int s = 0; s < 4; ++s) {
      float w = (s == 1 || s == 2) ? 2.0f : 1.0f;
      float c2n[4];
      #pragma unroll
      for (int nt = 0; nt < 4; ++nt) {
        float2 cc = c2Lds[nt * 16 + c];
        c2n[nt] = fmaf(cc.x, ts, cc.y);
      }

      #pragma unroll 1
      for (int p = 0; p < 2; ++p) {
        asm volatile("" ::: "memory");  // pin pair-invariant LDS loads per pair
        int mtA = 2 * p, mtB = 2 * p + 1;
        // zt for this lane's A-rows, via wave-local shuffle (point = mt*16+c)
        float sA0 = __shfl(zt0, mtA * 16 + c);
        float sA1 = __shfl(zt1, mtA * 16 + c);
        float sB0 = __shfl(zt0, mtB * 16 + c);
        float sB1 = __shfl(zt1, mtB * 16 + c);

        // ---- A-frags for both row-tiles, packed incrementally ----
        // SP: hi+lo (activation residual kept). SG: hi only.
        FragU SPhA[2], SPlA[2], SGhA[2];
        FragU SPhB[2], SPlB[2], SGhB[2];
        #pragma unroll
        for (int kt = 0; kt < 2; ++kt) {
          #pragma unroll
          for (int d = 0; d < 4; ++d) {
            float4 p0 = l1Lds[kt * 32 + g * 8 + 2 * d];
            float4 p1 = l1Lds[kt * 32 + g * 8 + 2 * d + 1];
            float b0 = fmaf(p0.x, ts, p0.w);
            float b1 = fmaf(p1.x, ts, p1.w);
            float spA0, sgA0, spA1, sgA1, spB0, sgB0, spB1, sgB1;
            l1chain(p0, b0, sA0, sA1, spA0, sgA0);
            l1chain(p1, b1, sA0, sA1, spA1, sgA1);
            l1chain(p0, b0, sB0, sB1, spB0, sgB0);
            l1chain(p1, b1, sB0, sB1, spB1, sgB1);
            pack2(spA0, spA1, SPhA[kt].u[d], SPlA[kt].u[d]);
            pack2(spB0, spB1, SPhB[kt].u[d], SPlB[kt].u[d]);
            SGhA[kt].u[d] = cvt_pk_bf16(sgA0, sgA1);
            SGhB[kt].u[d] = cvt_pk_bf16(sgB0, sgB1);
          }
        }

        // ---- GEMM1 both rows (2-term: (SPh + SPl) x Bh), shared B reads ----
        // Accumulators init with c2n (h2 = C1 directly afterwards).
        f32x4 C1A[4], C1B[4];
        #pragma unroll
        for (int nt = 0; nt < 4; ++nt) {
          C1A[nt] = (f32x4){c2n[nt], c2n[nt], c2n[nt], c2n[nt]};
          C1B[nt] = (f32x4){c2n[nt], c2n[nt], c2n[nt], c2n[nt]};
        }
        #pragma unroll
        for (int kt = 0; kt < 2; ++kt) {
          #pragma unroll
          for (int nt = 0; nt < 4; ++nt) {
            FragU Bh;
            Bh.u4 = fragLds[(kt * 4 + nt) * 64 + l];
            C1A[nt] = __builtin_amdgcn_mfma_f32_16x16x32_bf16(SPhA[kt].v, Bh.v, C1A[nt], 0, 0, 0);
            C1B[nt] = __builtin_amdgcn_mfma_f32_16x16x32_bf16(SPhB[kt].v, Bh.v, C1B[nt], 0, 0, 0);
            C1A[nt] = __builtin_amdgcn_mfma_f32_16x16x32_bf16(SPlA[kt].v, Bh.v, C1A[nt], 0, 0, 0);
            C1B[nt] = __builtin_amdgcn_mfma_f32_16x16x32_bf16(SPlB[kt].v, Bh.v, C1B[nt], 0, 0, 0);
          }
        }

        // ---- fused mid + GEMM2 per nt: g transient, zd/dv accumulate ----
        float zp0A[4] = {0.f, 0.f, 0.f, 0.f}, zp1A[4] = {0.f, 0.f, 0.f, 0.f};
        float zp0B[4] = {0.f, 0.f, 0.f, 0.f}, zp1B[4] = {0.f, 0.f, 0.f, 0.f};
        float dvA[4] = {0.f, 0.f, 0.f, 0.f}, dvB[4] = {0.f, 0.f, 0.f, 0.f};
        #pragma unroll
        for (int nt = 0; nt < 4; ++nt) {
          float2 l3 = l3Lds[nt * 16 + c];
          float gAr[4], gBr[4];
          #pragma unroll
          for (int r = 0; r < 4; ++r) {
            {
              float h2 = C1A[nt][r];
              float ex = __expf(-fabsf(h2));
              float lg = __logf(1.0f + ex);
              float sq = fmaxf(h2, 0.f) + lg;
              gAr[r] = 1.0f - __expf(-sq);  // sigmoid(h2)
              zp0A[r] = fmaf(l3.x, sq, zp0A[r]);
              zp1A[r] = fmaf(l3.y, sq, zp1A[r]);
            }
            {
              float h2 = C1B[nt][r];
              float ex = __expf(-fabsf(h2));
              float lg = __logf(1.0f + ex);
              float sq = fmaxf(h2, 0.f) + lg;
              gBr[r] = 1.0f - __expf(-sq);  // sigmoid(h2)
              zp0B[r] = fmaf(l3.x, sq, zp0B[r]);
              zp1B[r] = fmaf(l3.y, sq, zp1B[r]);
            }
          }
          // GEMM2 nt-tile (A = SGh, B = QT hi only)
          f32x4 C2A = (f32x4){0.f, 0.f, 0.f, 0.f};
          f32x4 C2B = (f32x4){0.f, 0.f, 0.f, 0.f};
          #pragma unroll
          for (int kt = 0; kt < 2; ++kt) {
            FragU Bh;
            Bh.u4 = fragLds[512 + (kt * 4 + nt) * 64 + l];
            C2A = __builtin_amdgcn_mfma_f32_16x16x32_bf16(SGhA[kt].v, Bh.v, C2A, 0, 0, 0);
            C2B = __builtin_amdgcn_mfma_f32_16x16x32_bf16(SGhB[kt].v, Bh.v, C2B, 0, 0, 0);
          }
          #pragma unroll
          for (int r = 0; r < 4; ++r) {
            dvA[r] = fmaf(C2A[r], gAr[r], dvA[r]);
            dvB[r] = fmaf(C2B[r], gBr[r], dvB[r]);
          }
        }

        // zd reduce + store
        #pragma unroll
        for (int r = 0; r < 4; ++r) {
          zp0A[r] = row_sum16(zp0A[r]); zp1A[r] = row_sum16(zp1A[r]);
          zp0B[r] = row_sum16(zp0B[r]); zp1B[r] = row_sum16(zp1B[r]);
        }
        if (c == 0) {
          #pragma unroll
          for (int r = 0; r < 4; ++r) {
            redLds[wid][0][mtA * 16 + g * 4 + r] = zp0A[r];
            redLds[wid][1][mtA * 16 + g * 4 + r] = zp1A[r];
            redLds[wid][0][mtB * 16 + g * 4 + r] = zp0B[r];
            redLds[wid][1][mtB * 16 + g * 4 + r] = zp1B[r];
          }
        }

        // Deferred dv: accumulate w-weighted partials; reduce at kernel end.
        // Uniform branch keeps accumulator indices compile-time (rule #20).
        if (p == 0) {
          #pragma unroll
          for (int r = 0; r < 4; ++r) {
            acc0A[r] = fmaf(w, dvA[r], acc0A[r]);
            acc0B[r] = fmaf(w, dvB[r], acc0B[r]);
          }
        } else {
          #pragma unroll
          for (int r = 0; r < 4; ++r) {
            acc1A[r] = fmaf(w, dvA[r], acc1A[r]);
            acc1B[r] = fmaf(w, dvB[r], acc1B[r]);
          }
        }
      }

      // ---- wave-local handoff: redLds writes -> reads (same wave only) ----
      WAVE_FENCE();

      // ---- owner: collect zd, RK4 ----
      float zd0 = redLds[wid][0][l] + fmaf(c30, ts, cb0);
      float zd1 = redLds[wid][1][l] + fmaf(c31, ts, cb1);

      az0 = fmaf(w, zd0, az0);
      az1 = fmaf(w, zd1, az1);
      if (s < 3) {
        float cc2 = (s == 2) ? dt : 0.5f * dt;
        zt0 = fmaf(cc2, zd0, z0);
        zt1 = fmaf(cc2, zd1, z1);
        ts = t0 + cc2;
      }
    }
    z0 = fmaf(dt / 6.0f, az0, z0);
    z1 = fmaf(dt / 6.0f, az1, z1);
  }

  // ---- final deferred dv reduction (once per kernel) ----
  #pragma unroll
  for (int r = 0; r < 4; ++r) {
    acc0A[r] = row_sum16(acc0A[r]);
    acc0B[r] = row_sum16(acc0B[r]);
    acc1A[r] = row_sum16(acc1A[r]);
    acc1B[r] = row_sum16(acc1B[r]);
  }
  if (c == 0) {
    #pragma unroll
    for (int r = 0; r < 4; ++r) {
      redLds[wid][0][0 * 16 + g * 4 + r] = acc0A[r];
      redLds[wid][0][1 * 16 + g * 4 + r] = acc0B[r];
      redLds[wid][0][2 * 16 + g * 4 + r] = acc1A[r];
      redLds[wid][0][3 * 16 + g * 4 + r] = acc1B[r];
    }
  }
  WAVE_FENCE();
  float alTot = redLds[wid][0][l];
  lp = fmaf(-dt / 6.0f, alTot, lp);  // k_l = -div, summed over all stages/steps

  if (pt < B) {
    out[2 * pt] = z0;
    out[2 * pt + 1] = z1;
    out[2 * B + pt] = lp;
  }
}

extern "C" void kernel_launch(void* const* d_in, const int* in_sizes, int n_in,
                              void* d_out, int out_size, void* d_ws, size_t ws_size,
                              hipStream_t stream) {
  const float* z   = (const float*)d_in[0];
  const float* dlp = (const float*)d_in[1];
  const float* W1  = (const float*)d_in[2];
  const float* b1  = (const float*)d_in[3];
  const float* W2  = (const float*)d_in[4];
  const float* b2  = (const float*)d_in[5];
  const float* W3  = (const float*)d_in[6];
  const float* b3  = (const float*)d_in[7];
  float* out = (float*)d_out;
  float* ws = (float*)d_ws;

  int B = in_sizes[0] / 2;

  ffjord_prep<<<1, 256, 0, stream>>>(W1, b1, W2, b2, W3, b3, ws);
  int blocks = (B + 255) / 256;  // 256 points per block, 64 per wave
  ffjord_main<<<blocks, 256, 0, stream>>>(z, dlp, ws, out, B);
}